// Round 1
// baseline (705.966 us; speedup 1.0000x reference)
//
#include <hip/hip_runtime.h>
#include <math.h>

// Problem constants: N=768 nodes, H=4 heads, D=3, HDIM=64, HID=64, d_in_e=164.
// e_in[i,j] = [ sqn_nodes(i,j,h) (4) | h_concat[j] (80) | h_concat[i] (80) ]
// Workspace layout (floats):
#define WS_HC    0        // h_concat [768][80]
#define WS_W0AT  61440    // phi_e_w0 rows 0..3 transposed   [64][4]
#define WS_W0BT  61696    // phi_e_w0 rows 4..83 transposed  [64][80]
#define WS_W1T   66816    // phi_e_w1 transposed             [64][64]
#define WS_X0T   70912    // phi_x_w0 transposed             [64][64]
#define WS_X1T   75008    // phi_x_w1 transposed             [64][64]
#define WS_X2T   79104    // phi_x_w2 transposed             [4][64]
#define WS_TOTAL 79360

__device__ __forceinline__ float silu_f(float v) {
    return v / (1.0f + __expf(-v));
}

// pack two floats to bf16 (RNE), low = a, high = b
__device__ __forceinline__ unsigned pack_bf2(float a, float b) {
    unsigned ua = __float_as_uint(a);
    unsigned ub = __float_as_uint(b);
    ua += 0x7FFFu + ((ua >> 16) & 1u);
    ub += 0x7FFFu + ((ub >> 16) & 1u);
    return (ua >> 16) | (ub & 0xFFFF0000u);
}
__device__ __forceinline__ float2 unpack_bf2(unsigned u) {
    return make_float2(__uint_as_float(u << 16), __uint_as_float(u & 0xFFFF0000u));
}

// ---------------- prep: h_concat + weight transposes ----------------
__global__ __launch_bounds__(256) void prep_kernel(
    const float* __restrict__ x, const float* __restrict__ h,
    const float* __restrict__ ew0, const float* __restrict__ ew1,
    const float* __restrict__ xw0, const float* __restrict__ xw1,
    const float* __restrict__ xw2, float* __restrict__ ws)
{
    int idx = blockIdx.x * 256 + threadIdx.x;
    if (idx < 61440) {
        int m = idx / 80, c = idx - m * 80;
        float v;
        if (c < 64) {
            v = h[m * 64 + c];
        } else {
            int t = c - 64;
            int i2 = t >> 2, j2 = t & 3;   // sq_norms_heads[m, i2, j2] = ||x[m,j2]-x[m,i2]||^2
            float d0 = x[m*12 + j2*3 + 0] - x[m*12 + i2*3 + 0];
            float d1 = x[m*12 + j2*3 + 1] - x[m*12 + i2*3 + 1];
            float d2 = x[m*12 + j2*3 + 2] - x[m*12 + i2*3 + 2];
            v = d0*d0 + d1*d1 + d2*d2;
        }
        ws[idx] = v;
    } else if (idx < WS_TOTAL) {
        int t = idx - 61440;
        float v;
        if (t < 256)        { int l = t >> 2, k = t & 3;              v = ew0[k*64 + l]; }
        else if (t < 5376)  { int u = t - 256;  int l = u / 80, k = u - l*80; v = ew0[(4+k)*64 + l]; }
        else if (t < 9472)  { int u = t - 5376; int l = u >> 6, k = u & 63;  v = ew1[k*64 + l]; }
        else if (t < 13568) { int u = t - 9472; int l = u >> 6, k = u & 63;  v = xw0[k*64 + l]; }
        else if (t < 17664) { int u = t - 13568;int l = u >> 6, k = u & 63;  v = xw1[k*64 + l]; }
        else                { int u = t - 17664;int l2 = u >> 6, k = u & 63; v = xw2[k*4 + l2]; }
        ws[61440 + t] = v;
    }
}

// Chunk-of-8 FMA against transposed weights (wave-uniform address -> s_load)
#define CHUNK8_FMA(WT, STRIDE, OFF)                                          \
    _Pragma("unroll")                                                        \
    for (int l = 0; l < 64; ++l) {                                           \
        const float* wr = (WT) + l * (STRIDE) + (OFF);                       \
        acc[l] += e[0]*wr[0] + e[1]*wr[1] + e[2]*wr[2] + e[3]*wr[3]          \
                + e[4]*wr[4] + e[5]*wr[5] + e[6]*wr[6] + e[7]*wr[7];         \
    }

// Read 8 staged activations (bf16 pairs, swizzled) into e[8]
#define READ_Y8(C)                                                           \
    {                                                                        \
        _Pragma("unroll")                                                    \
        for (int kk = 0; kk < 8; kk += 2) {                                  \
            int cidx = (8*(C) + kk + rot) & 63;                              \
            float2 f = unpack_bf2(ybuf[wv][lane][cidx >> 1]);                \
            e[kk] = f.x; e[kk+1] = f.y;                                      \
        }                                                                    \
    }

// ---------------- main fused kernel: one block per row i ----------------
__global__ __launch_bounds__(256, 3) void egcl_kernel(
    const float* __restrict__ x, const float* __restrict__ h,
    const float* __restrict__ ew0, const float* __restrict__ eb0,
    const float* __restrict__ eb1,
    const float* __restrict__ infw, const float* __restrict__ infb,
    const float* __restrict__ xb0, const float* __restrict__ xb1, const float* __restrict__ xb2,
    const float* __restrict__ hw0, const float* __restrict__ hb0,
    const float* __restrict__ hw1, const float* __restrict__ hb1,
    const float* __restrict__ hw2, const float* __restrict__ hb2,
    const float* __restrict__ ws, float* __restrict__ out)
{
    __shared__ unsigned ybuf[4][64][32];  // per-wave activation staging, bf16 pairs, swizzled
    __shared__ float ebuf[4][64];         // per-wave e_att
    __shared__ float base_l[64];          // b0 + hc[i] part of phi_e L0
    __shared__ float redm[4][64];         // cross-wave m_i partials
    __shared__ float reds[4][12];         // cross-wave shift partials
    __shared__ float inbuf[128];          // phi_h input [m_i | h[i]]
    __shared__ float zbuf[64];            // phi_h hidden

    const int i    = blockIdx.x;
    const int tid  = threadIdx.x;
    const int wv   = tid >> 6;
    const int lane = tid & 63;
    const int rot  = lane & 62;           // pair-preserving swizzle rotation

    const float* hc   = ws + WS_HC;
    const float* w0aT = ws + WS_W0AT;
    const float* w0bT = ws + WS_W0BT;
    const float* w1T  = ws + WS_W1T;
    const float* x0T  = ws + WS_X0T;
    const float* x1T  = ws + WS_X1T;
    const float* x2T  = ws + WS_X2T;

    // x[i] (uniform -> scalar loads)
    float xi[12];
    #pragma unroll
    for (int t = 0; t < 12; ++t) xi[t] = x[i*12 + t];

    if (wv == 0) {
        // base_l[l] = b0[l] + sum_k hc[i][k] * W0[84+k][l]   (hc[i] uniform -> s_load)
        float a = eb0[lane];
        const float* hci = hc + i * 80;
        #pragma unroll 4
        for (int k = 0; k < 80; ++k) a += hci[k] * ew0[(84+k)*64 + lane];
        base_l[lane] = a;
    } else if (wv == 1) {
        inbuf[64 + lane] = h[i*64 + lane];
    }
    __syncthreads();

    float macc = 0.0f;      // m_i partial for neuron `lane` (this wave's j's)
    float sacc[12];
    #pragma unroll
    for (int t = 0; t < 12; ++t) sacc[t] = 0.0f;

    for (int it = 0; it < 3; ++it) {
        const int jj = it * 256 + tid;

        // diff_nodes[i,jj] = x[jj] - x[i]; sqn per head
        float dx[12];
        {
            const float4* xp = (const float4*)(x + jj*12);
            float4 a = xp[0], b = xp[1], c = xp[2];
            dx[0]=a.x-xi[0]; dx[1]=a.y-xi[1]; dx[2]=a.z-xi[2];  dx[3]=a.w-xi[3];
            dx[4]=b.x-xi[4]; dx[5]=b.y-xi[5]; dx[6]=b.z-xi[6];  dx[7]=b.w-xi[7];
            dx[8]=c.x-xi[8]; dx[9]=c.y-xi[9]; dx[10]=c.z-xi[10];dx[11]=c.w-xi[11];
        }
        float sqn[4];
        #pragma unroll
        for (int hh = 0; hh < 4; ++hh)
            sqn[hh] = dx[hh*3]*dx[hh*3] + dx[hh*3+1]*dx[hh*3+1] + dx[hh*3+2]*dx[hh*3+2];

        float acc[64];

        // ---- phi_e layer 0 ----
        #pragma unroll
        for (int l = 0; l < 64; ++l)
            acc[l] = base_l[l] + sqn[0]*w0aT[l*4+0] + sqn[1]*w0aT[l*4+1]
                               + sqn[2]*w0aT[l*4+2] + sqn[3]*w0aT[l*4+3];
        {
            const float* hcj = hc + jj * 80;
            #pragma unroll 1
            for (int c = 0; c < 10; ++c) {
                float e[8];
                float4 A = *(const float4*)(hcj + 8*c);
                float4 B = *(const float4*)(hcj + 8*c + 4);
                e[0]=A.x; e[1]=A.y; e[2]=A.z; e[3]=A.w;
                e[4]=B.x; e[5]=B.y; e[6]=B.z; e[7]=B.w;
                CHUNK8_FMA(w0bT, 80, 8*c)
            }
        }
        // stage y = silu(acc)
        #pragma unroll
        for (int l = 0; l < 64; l += 2) {
            int cidx = (l + rot) & 63;
            ybuf[wv][lane][cidx >> 1] = pack_bf2(silu_f(acc[l]), silu_f(acc[l+1]));
        }

        // ---- phi_e layer 1 ----
        #pragma unroll
        for (int l = 0; l < 64; ++l) acc[l] = eb1[l];
        #pragma unroll 1
        for (int c = 0; c < 8; ++c) {
            float e[8];
            READ_Y8(c)
            CHUNK8_FMA(w1T, 64, 8*c)
        }

        // m = silu(acc): fuse phi_inf dot and stage m
        float s_inf = infb[0];
        #pragma unroll
        for (int l = 0; l < 64; l += 2) {
            float m0 = silu_f(acc[l]), m1 = silu_f(acc[l+1]);
            s_inf += m0 * infw[l] + m1 * infw[l+1];
            int cidx = (l + rot) & 63;
            ybuf[wv][lane][cidx >> 1] = pack_bf2(m0, m1);
        }
        float eatt = (jj == i) ? 0.0f : 1.0f / (1.0f + __expf(-s_inf));
        ebuf[wv][lane] = eatt;

        // ---- m_i partial: lane k sums e_j * m[j][k] over this wave's 64 j's ----
        #pragma unroll 1
        for (int j2 = 0; j2 < 64; ++j2) {
            float ev = ebuf[wv][j2];
            int cidx = (lane + (j2 & 62)) & 63;
            float2 f = unpack_bf2(ybuf[wv][j2][cidx >> 1]);
            macc += ev * ((cidx & 1) ? f.y : f.x);
        }

        // ---- phi_x layer 0 (reads m from ybuf) ----
        #pragma unroll
        for (int l = 0; l < 64; ++l) acc[l] = xb0[l];
        #pragma unroll 1
        for (int c = 0; c < 8; ++c) {
            float e[8];
            READ_Y8(c)
            CHUNK8_FMA(x0T, 64, 8*c)
        }
        // stage y2 (overwrites m; all m readers above are done — same-wave ordering)
        #pragma unroll
        for (int l = 0; l < 64; l += 2) {
            int cidx = (l + rot) & 63;
            ybuf[wv][lane][cidx >> 1] = pack_bf2(silu_f(acc[l]), silu_f(acc[l+1]));
        }

        // ---- phi_x layer 1 ----
        #pragma unroll
        for (int l = 0; l < 64; ++l) acc[l] = xb1[l];
        #pragma unroll 1
        for (int c = 0; c < 8; ++c) {
            float e[8];
            READ_Y8(c)
            CHUNK8_FMA(x1T, 64, 8*c)
        }

        // ---- phi_x layer 2 (64 -> 4), in registers ----
        float p[4] = { xb2[0], xb2[1], xb2[2], xb2[3] };
        #pragma unroll
        for (int l = 0; l < 64; ++l) {
            float yv = silu_f(acc[l]);
            p[0] += yv * x2T[0*64 + l];
            p[1] += yv * x2T[1*64 + l];
            p[2] += yv * x2T[2*64 + l];
            p[3] += yv * x2T[3*64 + l];
        }

        // ---- equivariant shift contributions + wave butterfly reduce ----
        float mask = (jj == i) ? 0.0f : 1.0f;
        #pragma unroll
        for (int hh = 0; hh < 4; ++hh) {
            float nsq = (sqn[hh] == 0.0f) ? 1.0f : sqn[hh];
            float inv = mask * p[hh] / (sqrtf(nsq) + 1.0f);
            #pragma unroll
            for (int d = 0; d < 3; ++d) {
                float v = dx[hh*3 + d] * inv;
                v += __shfl_xor(v, 1, 64);
                v += __shfl_xor(v, 2, 64);
                v += __shfl_xor(v, 4, 64);
                v += __shfl_xor(v, 8, 64);
                v += __shfl_xor(v, 16, 64);
                v += __shfl_xor(v, 32, 64);
                sacc[hh*3 + d] += v;
            }
        }
    }

    // cross-wave reduction
    redm[wv][lane] = macc;
    if (lane == 0) {
        #pragma unroll
        for (int t = 0; t < 12; ++t) reds[wv][t] = sacc[t];
    }
    __syncthreads();

    if (wv == 0) {
        // m_i and phi_h input
        float mi = (redm[0][lane] + redm[1][lane] + redm[2][lane] + redm[3][lane])
                   * (1.0f / sqrtf(767.0f));
        inbuf[lane] = mi;

        // x_new
        if (lane < 12) {
            float sh = reds[0][lane] + reds[1][lane] + reds[2][lane] + reds[3][lane];
            out[i*12 + lane] = x[i*12 + lane] + sh * (1.0f / 767.0f);
        }

        // phi_h MLP (lane = output neuron)
        float a = hb0[lane];
        #pragma unroll 8
        for (int k = 0; k < 128; ++k) a += inbuf[k] * hw0[k*64 + lane];
        zbuf[lane] = silu_f(a);

        a = hb1[lane];
        #pragma unroll 8
        for (int k = 0; k < 64; ++k) a += zbuf[k] * hw1[k*64 + lane];
        zbuf[lane] = silu_f(a);   // same-wave in-order: all reads above complete first

        a = hb2[lane];
        #pragma unroll 8
        for (int k = 0; k < 64; ++k) a += zbuf[k] * hw2[k*64 + lane];
        out[9216 + i*64 + lane] = h[i*64 + lane] + a;
    }
}

extern "C" void kernel_launch(void* const* d_in, const int* in_sizes, int n_in,
                              void* d_out, int out_size, void* d_ws, size_t ws_size,
                              hipStream_t stream) {
    const float* x    = (const float*)d_in[0];
    const float* h    = (const float*)d_in[1];
    const float* ew0  = (const float*)d_in[2];
    const float* eb0  = (const float*)d_in[3];
    const float* ew1  = (const float*)d_in[4];
    const float* eb1  = (const float*)d_in[5];
    const float* infw = (const float*)d_in[6];
    const float* infb = (const float*)d_in[7];
    const float* xw0  = (const float*)d_in[8];
    const float* xb0  = (const float*)d_in[9];
    const float* xw1  = (const float*)d_in[10];
    const float* xb1  = (const float*)d_in[11];
    const float* xw2  = (const float*)d_in[12];
    const float* xb2  = (const float*)d_in[13];
    const float* hw0  = (const float*)d_in[14];
    const float* hb0  = (const float*)d_in[15];
    const float* hw1  = (const float*)d_in[16];
    const float* hb1  = (const float*)d_in[17];
    const float* hw2  = (const float*)d_in[18];
    const float* hb2  = (const float*)d_in[19];

    float* ws  = (float*)d_ws;
    float* out = (float*)d_out;

    prep_kernel<<<(WS_TOTAL + 255) / 256, 256, 0, stream>>>(x, h, ew0, ew1, xw0, xw1, xw2, ws);
    egcl_kernel<<<768, 256, 0, stream>>>(x, h, ew0, eb0, eb1, infw, infb,
                                         xb0, xb1, xb2,
                                         hw0, hb0, hw1, hb1, hw2, hb2,
                                         ws, out);
}

// Round 2
// 275.627 us; speedup vs baseline: 2.5613x; 2.5613x over previous
//
#include <hip/hip_runtime.h>
#include <math.h>

// N=768, H=4, D=3, HDIM=64, HID=64, d_in_e=164.
// e_in[i,j] = [ sqn(4) | hc[j](80) | hc[i](80) ]
//  z0 = sqn@W0a + Bj[j] + Bi[i]   (Bi includes b0)
//
// ws layout (float offsets):
#define WS_BJ    0         // Bj [768][64] f32
#define WS_BI    49152     // Bi [768][64] f32
#define WS_W0AT  98304     // W0a^T [64 l][4 h] f32
#define WS_WB_F  98560     // bf16 weights (ushort), 224 rows x 64 k, XOR-swizzled
                           // rows: [0,64)=W1^T, [64,144)=X0^T|infw|pad, [144,208)=X1^T, [208,224)=X2^T|pad

typedef unsigned short ushort_t;
typedef __attribute__((ext_vector_type(8))) __bf16 bf16x8;
typedef __attribute__((ext_vector_type(4))) float f32x4;

__device__ __forceinline__ float silu_f(float v) { return v / (1.0f + __expf(-v)); }

__device__ __forceinline__ ushort_t bf16r(float f) {
    unsigned u = __float_as_uint(f);
    u += 0x7FFFu + ((u >> 16) & 1u);
    return (ushort_t)(u >> 16);
}
__device__ __forceinline__ float bf2f(ushort_t s) { return __uint_as_float(((unsigned)s) << 16); }

__device__ __forceinline__ unsigned pack_bf2(float a, float b) {
    unsigned ua = __float_as_uint(a), ub = __float_as_uint(b);
    ua += 0x7FFFu + ((ua >> 16) & 1u);
    ub += 0x7FFFu + ((ub >> 16) & 1u);
    return (ua >> 16) | (ub & 0xFFFF0000u);
}

// ---------------- prep: Bi/Bj GEMVs + bf16 weight swizzle ----------------
__global__ __launch_bounds__(64) void prep_kernel(
    const float* __restrict__ x, const float* __restrict__ h,
    const float* __restrict__ ew0, const float* __restrict__ eb0,
    const float* __restrict__ ew1, const float* __restrict__ infw,
    const float* __restrict__ xw0, const float* __restrict__ xw1,
    const float* __restrict__ xw2, float* __restrict__ ws)
{
    const int blk = blockIdx.x, t = threadIdx.x;
    if (blk < 768) {
        __shared__ float hcs[80];
        const int m = blk;
        hcs[t] = h[m * 64 + t];
        if (t < 16) {
            int i2 = t >> 2, j2 = t & 3;
            float d0 = x[m*12 + j2*3 + 0] - x[m*12 + i2*3 + 0];
            float d1 = x[m*12 + j2*3 + 1] - x[m*12 + i2*3 + 1];
            float d2 = x[m*12 + j2*3 + 2] - x[m*12 + i2*3 + 2];
            hcs[64 + t] = d0*d0 + d1*d1 + d2*d2;
        }
        __syncthreads();
        float bj = 0.0f, bi = eb0[t];
        #pragma unroll 4
        for (int k = 0; k < 80; ++k) {
            float hv = hcs[k];
            bj += hv * ew0[(4 + k) * 64 + t];
            bi += hv * ew0[(84 + k) * 64 + t];
        }
        ws[WS_BJ + m * 64 + t] = bj;
        ws[WS_BI + m * 64 + t] = bi;
    } else if (blk < 800) {
        ushort_t* wb = (ushort_t*)(ws + WS_WB_F);
        #pragma unroll 1
        for (int tt = 0; tt < 7; ++tt) {
            int e = (blk - 768) * 448 + tt * 64 + t;   // < 14336
            int n = e >> 6, k = e & 63;
            float v;
            if (n < 64)       v = ew1[k * 64 + n];
            else if (n < 144) { int n2 = n - 64;  v = (n2 < 64) ? xw0[k*64 + n2] : (n2 == 64 ? infw[k] : 0.0f); }
            else if (n < 208) v = xw1[k * 64 + (n - 144)];
            else              { int n2 = n - 208; v = (n2 < 4) ? xw2[k*4 + n2] : 0.0f; }
            wb[n * 64 + (((k >> 3) ^ (n & 7)) << 3) + (k & 7)] = bf16r(v);
        }
    } else {
        #pragma unroll
        for (int hh = 0; hh < 4; ++hh) ws[WS_W0AT + t * 4 + hh] = ew0[hh * 64 + t];
    }
}

// GEMM: C[64 rows][NCT*16 cols] += A(yb [64rows][64k] swizzled bf16) * B(wb [n][64k] swizzled bf16)
template<int NCT>
__device__ __forceinline__ void gemm16(const ushort_t* yb, const ushort_t* wb,
                                       int lane, f32x4* acc /* [4*NCT] */)
{
    const int ml = lane & 15, q = lane >> 4;
    bf16x8 af[4][2];
    #pragma unroll
    for (int rt = 0; rt < 4; ++rt) {
        int m = rt * 16 + ml;
        #pragma unroll
        for (int kt = 0; kt < 2; ++kt) {
            int b = kt * 4 + q;
            af[rt][kt] = *(const bf16x8*)(yb + m * 64 + ((b ^ (m & 7)) << 3));
        }
    }
    #pragma unroll
    for (int ct = 0; ct < NCT; ++ct) {
        int n = ct * 16 + ml;
        bf16x8 bf0 = *(const bf16x8*)(wb + n * 64 + (((0 + q) ^ (n & 7)) << 3));
        bf16x8 bf1 = *(const bf16x8*)(wb + n * 64 + (((4 + q) ^ (n & 7)) << 3));
        #pragma unroll
        for (int rt = 0; rt < 4; ++rt) {
            acc[rt*NCT + ct] = __builtin_amdgcn_mfma_f32_16x16x32_bf16(af[rt][0], bf0, acc[rt*NCT + ct], 0, 0, 0);
            acc[rt*NCT + ct] = __builtin_amdgcn_mfma_f32_16x16x32_bf16(af[rt][1], bf1, acc[rt*NCT + ct], 0, 0, 0);
        }
    }
}

// silu + bf16 + swizzled store of C tiles (cols 0..63) back into yb
template<int S>
__device__ __forceinline__ void write_silu(ushort_t* yb, int lane, const f32x4* acc)
{
    const int ml = lane & 15, q = lane >> 4;
    #pragma unroll
    for (int rt = 0; rt < 4; ++rt) {
        #pragma unroll
        for (int ct = 0; ct < 4; ++ct) {
            f32x4 a = acc[rt*S + ct];
            #pragma unroll
            for (int reg = 0; reg < 4; ++reg) {
                int r = rt * 16 + q * 4 + reg;
                int c = ct * 16 + ml;
                yb[r * 64 + (((c >> 3) ^ (r & 7)) << 3) + (c & 7)] = bf16r(silu_f(a[reg]));
            }
        }
    }
}

// ---------------- main fused kernel: one block per row i ----------------
__global__ __launch_bounds__(256, 2) void egcl_kernel(
    const float* __restrict__ x, const float* __restrict__ h,
    const float* __restrict__ eb1, const float* __restrict__ infb,
    const float* __restrict__ xb0, const float* __restrict__ xb1, const float* __restrict__ xb2,
    const float* __restrict__ hw0, const float* __restrict__ hb0,
    const float* __restrict__ hw1, const float* __restrict__ hb1,
    const float* __restrict__ hw2, const float* __restrict__ hb2,
    const float* __restrict__ ws, float* __restrict__ out)
{
    __shared__ ushort_t wbuf[14336];     // swizzled bf16 weights
    __shared__ ushort_t ybuf[4][4096];   // per-wave activations [64 r][64 k], swizzled
    __shared__ float sbuf[4][64];        // s_inf -> e per wave
    __shared__ float pbuf[4][320];       // p [64][5-padded] per wave
    __shared__ float redm[4][64];
    __shared__ float reds[4][12];
    __shared__ float inbuf[128];
    __shared__ float zbuf[64];

    const int i = blockIdx.x, tid = threadIdx.x;
    const int wv = tid >> 6, lane = tid & 63;
    const int ml = lane & 15, q = lane >> 4;

    // stage weights (14336 ushorts = 1792 uint4)
    {
        const uint4* src = (const uint4*)((const ushort_t*)(ws + WS_WB_F));
        uint4* dst = (uint4*)wbuf;
        #pragma unroll
        for (int t7 = 0; t7 < 7; ++t7) dst[t7 * 256 + tid] = src[t7 * 256 + tid];
    }
    if (wv == 1) inbuf[64 + lane] = h[i * 64 + lane];
    __syncthreads();

    float xi[12];
    #pragma unroll
    for (int t = 0; t < 12; ++t) xi[t] = x[i * 12 + t];

    const float* Bi   = ws + WS_BI + i * 64;   // uniform -> s_load
    const float* w0at = ws + WS_W0AT;          // uniform -> s_load
    ushort_t* yb = ybuf[wv];

    float macc = 0.0f;
    float sacc[12];
    #pragma unroll
    for (int t = 0; t < 12; ++t) sacc[t] = 0.0f;

    for (int it = 0; it < 3; ++it) {
        const int jg = it * 256 + wv * 64 + lane;

        float dx[12];
        {
            const float4* xp = (const float4*)(x + jg * 12);
            float4 a = xp[0], b = xp[1], c = xp[2];
            dx[0]=a.x-xi[0]; dx[1]=a.y-xi[1]; dx[2]=a.z-xi[2];  dx[3]=a.w-xi[3];
            dx[4]=b.x-xi[4]; dx[5]=b.y-xi[5]; dx[6]=b.z-xi[6];  dx[7]=b.w-xi[7];
            dx[8]=c.x-xi[8]; dx[9]=c.y-xi[9]; dx[10]=c.z-xi[10];dx[11]=c.w-xi[11];
        }
        float sqn[4];
        #pragma unroll
        for (int hh = 0; hh < 4; ++hh)
            sqn[hh] = dx[hh*3]*dx[hh*3] + dx[hh*3+1]*dx[hh*3+1] + dx[hh*3+2]*dx[hh*3+2];

        // ---- phi_e L0 on VALU (K=4 + Bi + Bj), stream in blocks of 8 ----
        {
            const float* Bj = ws + WS_BJ + jg * 64;
            #pragma unroll
            for (int b = 0; b < 8; ++b) {
                float zz[8];
                #pragma unroll
                for (int u = 0; u < 8; ++u) {
                    int l = b * 8 + u;
                    float v = Bi[l] + Bj[l]
                            + sqn[0]*w0at[l*4+0] + sqn[1]*w0at[l*4+1]
                            + sqn[2]*w0at[l*4+2] + sqn[3]*w0at[l*4+3];
                    zz[u] = silu_f(v);
                }
                uint4 pk = make_uint4(pack_bf2(zz[0], zz[1]), pack_bf2(zz[2], zz[3]),
                                      pack_bf2(zz[4], zz[5]), pack_bf2(zz[6], zz[7]));
                *(uint4*)(yb + lane * 64 + ((b ^ (lane & 7)) << 3)) = pk;
            }
        }

        // ---- phi_e L1 ----
        f32x4 acc1[16];
        #pragma unroll
        for (int ct = 0; ct < 4; ++ct) {
            float bv = eb1[ct * 16 + ml];
            #pragma unroll
            for (int rt = 0; rt < 4; ++rt) acc1[rt*4 + ct] = f32x4{bv, bv, bv, bv};
        }
        gemm16<4>(yb, wbuf + 0, lane, acc1);
        write_silu<4>(yb, lane, acc1);               // m -> yb

        // ---- phi_x L0 + phi_inf (col 64) ----
        f32x4 acc0[20];
        #pragma unroll
        for (int ct = 0; ct < 5; ++ct) {
            float bv = (ct < 4) ? xb0[ct * 16 + ml] : ((ml == 0) ? infb[0] : 0.0f);
            #pragma unroll
            for (int rt = 0; rt < 4; ++rt) acc0[rt*5 + ct] = f32x4{bv, bv, bv, bv};
        }
        gemm16<5>(yb, wbuf + 4096, lane, acc0);

        // route s_inf -> e (lane=j layout)
        if (ml == 0) {
            #pragma unroll
            for (int rt = 0; rt < 4; ++rt)
                #pragma unroll
                for (int reg = 0; reg < 4; ++reg)
                    sbuf[wv][rt*16 + q*4 + reg] = acc0[rt*5 + 4][reg];
        }
        {
            float sv = sbuf[wv][lane];
            float ea = (jg == i) ? 0.0f : 1.0f / (1.0f + __expf(-sv));
            sbuf[wv][lane] = ea;
        }

        // ---- m_i partial (m still in yb): lane=l sums e_j * m[j][l] ----
        #pragma unroll 8
        for (int j2 = 0; j2 < 64; ++j2) {
            float ev = sbuf[wv][j2];
            ushort_t mv = yb[j2 * 64 + (((lane >> 3) ^ (j2 & 7)) << 3) + (lane & 7)];
            macc += ev * bf2f(mv);
        }

        write_silu<5>(yb, lane, acc0);               // y1 -> yb (m dead now)

        // ---- phi_x L1 ----
        f32x4 acc2[16];
        #pragma unroll
        for (int ct = 0; ct < 4; ++ct) {
            float bv = xb1[ct * 16 + ml];
            #pragma unroll
            for (int rt = 0; rt < 4; ++rt) acc2[rt*4 + ct] = f32x4{bv, bv, bv, bv};
        }
        gemm16<4>(yb, wbuf + 9216, lane, acc2);
        write_silu<4>(yb, lane, acc2);               // y2 -> yb

        // ---- phi_x L2 (64 -> 4) ----
        f32x4 accp[4];
        {
            float bv = (ml < 4) ? xb2[ml] : 0.0f;
            #pragma unroll
            for (int rt = 0; rt < 4; ++rt) accp[rt] = f32x4{bv, bv, bv, bv};
        }
        gemm16<1>(yb, wbuf + 13312, lane, accp);
        if (ml < 4) {
            #pragma unroll
            for (int rt = 0; rt < 4; ++rt)
                #pragma unroll
                for (int reg = 0; reg < 4; ++reg)
                    pbuf[wv][(rt*16 + q*4 + reg) * 5 + ml] = accp[rt][reg];
        }

        // ---- shift contributions (lane=j) + wave butterfly ----
        {
            float pv[4];
            #pragma unroll
            for (int hh = 0; hh < 4; ++hh) pv[hh] = pbuf[wv][lane * 5 + hh];
            float mask = (jg == i) ? 0.0f : 1.0f;
            #pragma unroll
            for (int hh = 0; hh < 4; ++hh) {
                float nsq = (sqn[hh] == 0.0f) ? 1.0f : sqn[hh];
                float inv = mask * pv[hh] / (sqrtf(nsq) + 1.0f);
                #pragma unroll
                for (int d = 0; d < 3; ++d) {
                    float v = dx[hh*3 + d] * inv;
                    v += __shfl_xor(v, 1, 64);
                    v += __shfl_xor(v, 2, 64);
                    v += __shfl_xor(v, 4, 64);
                    v += __shfl_xor(v, 8, 64);
                    v += __shfl_xor(v, 16, 64);
                    v += __shfl_xor(v, 32, 64);
                    sacc[hh*3 + d] += v;
                }
            }
        }
    }

    // cross-wave reduction + tail
    redm[wv][lane] = macc;
    if (lane == 0) {
        #pragma unroll
        for (int t = 0; t < 12; ++t) reds[wv][t] = sacc[t];
    }
    __syncthreads();

    if (wv == 0) {
        float mi = (redm[0][lane] + redm[1][lane] + redm[2][lane] + redm[3][lane])
                   * (1.0f / sqrtf(767.0f));
        inbuf[lane] = mi;

        if (lane < 12) {
            float sh = reds[0][lane] + reds[1][lane] + reds[2][lane] + reds[3][lane];
            out[i*12 + lane] = x[i*12 + lane] + sh * (1.0f / 767.0f);
        }

        float a = hb0[lane];
        #pragma unroll 8
        for (int k = 0; k < 128; ++k) a += inbuf[k] * hw0[k*64 + lane];
        zbuf[lane] = silu_f(a);

        a = hb1[lane];
        #pragma unroll 8
        for (int k = 0; k < 64; ++k) a += zbuf[k] * hw1[k*64 + lane];
        zbuf[lane] = silu_f(a);

        a = hb2[lane];
        #pragma unroll 8
        for (int k = 0; k < 64; ++k) a += zbuf[k] * hw2[k*64 + lane];
        out[9216 + i*64 + lane] = h[i*64 + lane] + a;
    }
}

extern "C" void kernel_launch(void* const* d_in, const int* in_sizes, int n_in,
                              void* d_out, int out_size, void* d_ws, size_t ws_size,
                              hipStream_t stream) {
    const float* x    = (const float*)d_in[0];
    const float* h    = (const float*)d_in[1];
    const float* ew0  = (const float*)d_in[2];
    const float* eb0  = (const float*)d_in[3];
    const float* ew1  = (const float*)d_in[4];
    const float* eb1  = (const float*)d_in[5];
    const float* infw = (const float*)d_in[6];
    const float* infb = (const float*)d_in[7];
    const float* xw0  = (const float*)d_in[8];
    const float* xb0  = (const float*)d_in[9];
    const float* xw1  = (const float*)d_in[10];
    const float* xb1  = (const float*)d_in[11];
    const float* xw2  = (const float*)d_in[12];
    const float* xb2  = (const float*)d_in[13];
    const float* hw0  = (const float*)d_in[14];
    const float* hb0  = (const float*)d_in[15];
    const float* hw1  = (const float*)d_in[16];
    const float* hb1  = (const float*)d_in[17];
    const float* hw2  = (const float*)d_in[18];
    const float* hb2  = (const float*)d_in[19];

    float* ws  = (float*)d_ws;
    float* out = (float*)d_out;

    prep_kernel<<<801, 64, 0, stream>>>(x, h, ew0, eb0, ew1, infw, xw0, xw1, xw2, ws);
    egcl_kernel<<<768, 256, 0, stream>>>(x, h, eb1, infb, xb0, xb1, xb2,
                                         hw0, hb0, hw1, hb1, hw2, hb2,
                                         ws, out);
}

// Round 3
// 224.377 us; speedup vs baseline: 3.1463x; 1.2284x over previous
//
#include <hip/hip_runtime.h>
#include <hip/hip_bf16.h>
#include <math.h>

// N=768, H=4, D=3, HDIM=64, HID=64. e_in[i,j] = [sqn(4) | hc[j](80) | hc[i](80)]
// z0 = sqn@W0a + Bj[j] + Bi[i]  (Bi includes b0 and the hc[i] half)
//
// MFMA role-swap scheme: A = weights (rows = output features), B = activations
// stored [p][k] k-contiguous with stride 72 (pad). D[row=n'][col=p]: lane's
// f32x4 = 4 consecutive n' at fixed p -> packed ds_write_b64 to [p][n'];
// next layer reads ds_read_b128 from the same layout. No transpose anywhere.
//
// ws layout (float offsets):
#define WS_BJ    0         // Bj [768][64] f32
#define WS_BI    49152     // Bi [768][64] f32
#define WS_W0AT  98304     // W0a^T [64][4] f32
#define WS_BIAS  98560     // bias_all [224] f32 (matches wbuf rows)
#define WS_WB    98784     // bf16 wbuf image: 224 rows x 72 (pad to 16384 ushorts)
// wbuf rows: [0,64)=W1^T, [64,128)=X0^T, 128=infw, (128,144)=0,
//            [144,208)=X1^T, [208,212)=X2^T, [212,224)=0

typedef unsigned short ushort_t;
typedef __attribute__((ext_vector_type(8))) __bf16 bf16x8;
typedef __attribute__((ext_vector_type(4))) float f32x4;

__device__ __forceinline__ float silu_f(float v) { return v / (1.0f + __expf(-v)); }

__device__ __forceinline__ ushort_t bf16r(float f) {
    unsigned u = __float_as_uint(f);
    u += 0x7FFFu + ((u >> 16) & 1u);
    return (ushort_t)(u >> 16);
}
__device__ __forceinline__ float bf2f(ushort_t s) { return __uint_as_float(((unsigned)s) << 16); }

__device__ __forceinline__ unsigned pk2(float a, float b) {
    __hip_bfloat162 t = __float22bfloat162_rn(make_float2(a, b));
    return *reinterpret_cast<unsigned*>(&t);
}

// ---------------- prep ----------------
__global__ __launch_bounds__(64) void prep_kernel(
    const float* __restrict__ x, const float* __restrict__ h,
    const float* __restrict__ ew0, const float* __restrict__ eb0,
    const float* __restrict__ ew1, const float* __restrict__ eb1,
    const float* __restrict__ infw, const float* __restrict__ infb,
    const float* __restrict__ xw0, const float* __restrict__ xb0,
    const float* __restrict__ xw1, const float* __restrict__ xb1,
    const float* __restrict__ xw2, const float* __restrict__ xb2,
    float* __restrict__ ws)
{
    const int blk = blockIdx.x, t = threadIdx.x;
    if (blk < 768) {
        __shared__ float hcs[80];
        const int m = blk;
        hcs[t] = h[m * 64 + t];
        if (t < 16) {
            int i2 = t >> 2, j2 = t & 3;
            float d0 = x[m*12 + j2*3 + 0] - x[m*12 + i2*3 + 0];
            float d1 = x[m*12 + j2*3 + 1] - x[m*12 + i2*3 + 1];
            float d2 = x[m*12 + j2*3 + 2] - x[m*12 + i2*3 + 2];
            hcs[64 + t] = d0*d0 + d1*d1 + d2*d2;
        }
        __syncthreads();
        float bj = 0.0f, bi = eb0[t];
        #pragma unroll 4
        for (int k = 0; k < 80; ++k) {
            float hv = hcs[k];
            bj += hv * ew0[(4 + k) * 64 + t];
            bi += hv * ew0[(84 + k) * 64 + t];
        }
        ws[WS_BJ + m * 64 + t] = bj;
        ws[WS_BI + m * 64 + t] = bi;
    } else if (blk == 768) {
        #pragma unroll
        for (int hh = 0; hh < 4; ++hh) ws[WS_W0AT + t * 4 + hh] = ew0[hh * 64 + t];
        #pragma unroll
        for (int u = 0; u < 4; ++u) {
            int idx = u * 64 + t;
            if (idx < 224) {
                float v;
                if (idx < 64)       v = eb1[idx];
                else if (idx < 128) v = xb0[idx - 64];
                else if (idx == 128) v = infb[0];
                else if (idx < 144) v = 0.0f;
                else if (idx < 208) v = xb1[idx - 144];
                else if (idx < 212) v = xb2[idx - 208];
                else                v = 0.0f;
                ws[WS_BIAS + idx] = v;
            }
        }
    } else {
        ushort_t* wb = (ushort_t*)(ws + WS_WB);
        #pragma unroll 1
        for (int u = 0; u < 8; ++u) {
            int e = (blk - 769) * 512 + u * 64 + t;   // < 16384
            float v = 0.0f;
            if (e < 16128) {
                int r = e / 72, k = e - r * 72;
                if (k < 64) {
                    if (r < 64)        v = ew1[k * 64 + r];
                    else if (r < 128)  v = xw0[k * 64 + (r - 64)];
                    else if (r == 128) v = infw[k];
                    else if (r < 144)  v = 0.0f;
                    else if (r < 208)  v = xw1[k * 64 + (r - 144)];
                    else if (r < 212)  v = xw2[k * 4 + (r - 208)];
                }
            }
            wb[e] = bf16r(v);
        }
    }
}

// B-frags: activations yb[p][k], stride 72, k = kt*32 + q*8 + j
__device__ __forceinline__ void load_bfrags(const ushort_t* yb, int ml, int q, bf16x8 B[4][2]) {
    #pragma unroll
    for (int pt = 0; pt < 4; ++pt)
        #pragma unroll
        for (int kt = 0; kt < 2; ++kt)
            B[pt][kt] = *(const bf16x8*)(yb + (pt*16 + ml) * 72 + kt*32 + q*8);
}

// D += W^T(rows from wrow) * B ; acc[mt*4+pt]
template<int NMT>
__device__ __forceinline__ void gemmW(const ushort_t* wrow, int ml, int q,
                                      const bf16x8 B[4][2], f32x4* acc) {
    #pragma unroll
    for (int mt = 0; mt < NMT; ++mt) {
        #pragma unroll
        for (int kt = 0; kt < 2; ++kt) {
            bf16x8 af = *(const bf16x8*)(wrow + (mt*16 + ml) * 72 + kt*32 + q*8);
            #pragma unroll
            for (int pt = 0; pt < 4; ++pt)
                acc[mt*4 + pt] = __builtin_amdgcn_mfma_f32_16x16x32_bf16(af, B[pt][kt], acc[mt*4 + pt], 0, 0, 0);
        }
    }
}

// epilogue: y[p][n'] = bf16(silu(acc + bias)), packed b64 writes
__device__ __forceinline__ void ep_silu4(ushort_t* yb, int ml, int q,
                                         const f32x4* acc, const float4* bias) {
    #pragma unroll
    for (int mt = 0; mt < 4; ++mt) {
        float4 bv = bias[mt];
        #pragma unroll
        for (int pt = 0; pt < 4; ++pt) {
            f32x4 a = acc[mt*4 + pt];
            unsigned p0 = pk2(silu_f(a[0] + bv.x), silu_f(a[1] + bv.y));
            unsigned p1 = pk2(silu_f(a[2] + bv.z), silu_f(a[3] + bv.w));
            *(uint2*)(yb + (pt*16 + ml) * 72 + mt*16 + q*4) = make_uint2(p0, p1);
        }
    }
}

// ---------------- main fused kernel: one block per row i ----------------
__global__ __launch_bounds__(256, 2) void egcl_kernel(
    const float* __restrict__ x, const float* __restrict__ h,
    const float* __restrict__ hw0, const float* __restrict__ hb0,
    const float* __restrict__ hw1, const float* __restrict__ hb1,
    const float* __restrict__ hw2, const float* __restrict__ hb2,
    const float* __restrict__ ws, float* __restrict__ out)
{
    __shared__ ushort_t wbuf[16384];      // 32 KB swizzle-free padded weights
    __shared__ ushort_t ybuf[4][4608];    // per-wave acts [64 p][72], 9 KB each
    __shared__ float sbuf[4][64];
    __shared__ float pbuf[4][256];
    __shared__ float redm[4][64];
    __shared__ float reds[4][12];
    __shared__ float inbuf[128];
    __shared__ float zbuf[64];

    const int i = blockIdx.x, tid = threadIdx.x;
    const int wv = tid >> 6, lane = tid & 63;
    const int ml = lane & 15, q = lane >> 4;

    // stage weights (2048 uint4)
    {
        const uint4* src = (const uint4*)(ws + WS_WB);
        uint4* dst = (uint4*)wbuf;
        #pragma unroll
        for (int t8 = 0; t8 < 8; ++t8) dst[t8 * 256 + tid] = src[t8 * 256 + tid];
    }
    if (wv == 1) inbuf[64 + lane] = h[i * 64 + lane];
    __syncthreads();

    // bias fragments (rows n' = base + mt*16 + q*4 + reg)
    const float* bias = ws + WS_BIAS;
    float4 b_l1[4], b_x0[4], b_x1[4], b_x2;
    #pragma unroll
    for (int mt = 0; mt < 4; ++mt) {
        b_l1[mt] = *(const float4*)(bias + 0   + mt*16 + q*4);
        b_x0[mt] = *(const float4*)(bias + 64  + mt*16 + q*4);
        b_x1[mt] = *(const float4*)(bias + 144 + mt*16 + q*4);
    }
    b_x2 = *(const float4*)(bias + 208 + q*4);
    const float binf = bias[128];

    float xi[12];
    #pragma unroll
    for (int t = 0; t < 12; ++t) xi[t] = x[i * 12 + t];

    const float* Bi   = ws + WS_BI + i * 64;   // uniform -> s_load
    const float* w0at = ws + WS_W0AT;          // uniform -> s_load
    ushort_t* yb = ybuf[wv];

    float macc = 0.0f;
    float sacc[12];
    #pragma unroll
    for (int t = 0; t < 12; ++t) sacc[t] = 0.0f;

    #pragma unroll 1
    for (int it = 0; it < 3; ++it) {
        const int jg = it * 256 + wv * 64 + lane;

        float dx[12];
        {
            const float4* xp = (const float4*)(x + jg * 12);
            float4 a = xp[0], b = xp[1], c = xp[2];
            dx[0]=a.x-xi[0]; dx[1]=a.y-xi[1]; dx[2]=a.z-xi[2];  dx[3]=a.w-xi[3];
            dx[4]=b.x-xi[4]; dx[5]=b.y-xi[5]; dx[6]=b.z-xi[6];  dx[7]=b.w-xi[7];
            dx[8]=c.x-xi[8]; dx[9]=c.y-xi[9]; dx[10]=c.z-xi[10];dx[11]=c.w-xi[11];
        }
        float sqn[4];
        #pragma unroll
        for (int hh = 0; hh < 4; ++hh)
            sqn[hh] = dx[hh*3]*dx[hh*3] + dx[hh*3+1]*dx[hh*3+1] + dx[hh*3+2]*dx[hh*3+2];

        // ---- phi_e L0 (VALU, K=4 + Bi + Bj); write y0[p=lane][k] b128-packed ----
        {
            const float* Bj = ws + WS_BJ + jg * 64;
            #pragma unroll
            for (int b = 0; b < 8; ++b) {
                float4 A = *(const float4*)(Bj + b*8);
                float4 Bv = *(const float4*)(Bj + b*8 + 4);
                float z[8] = {A.x, A.y, A.z, A.w, Bv.x, Bv.y, Bv.z, Bv.w};
                #pragma unroll
                for (int u = 0; u < 8; ++u) {
                    int l = b*8 + u;
                    float v = Bi[l] + z[u]
                            + sqn[0]*w0at[l*4+0] + sqn[1]*w0at[l*4+1]
                            + sqn[2]*w0at[l*4+2] + sqn[3]*w0at[l*4+3];
                    z[u] = silu_f(v);
                }
                uint4 pkv = make_uint4(pk2(z[0],z[1]), pk2(z[2],z[3]),
                                       pk2(z[4],z[5]), pk2(z[6],z[7]));
                *(uint4*)(yb + lane * 72 + b*8) = pkv;
            }
        }

        bf16x8 B[4][2];
        f32x4 acc[16];

        // ---- phi_e L1: m = silu(y0 @ W1 + b1) ----
        load_bfrags(yb, ml, q, B);
        #pragma unroll
        for (int t = 0; t < 16; ++t) acc[t] = f32x4{0.f, 0.f, 0.f, 0.f};
        gemmW<4>(wbuf + 0, ml, q, B, acc);
        ep_silu4(yb, ml, q, acc, b_l1);

        // ---- phi_x L0 + phi_inf (B = m) ----
        load_bfrags(yb, ml, q, B);
        f32x4 accI[4];
        #pragma unroll
        for (int t = 0; t < 16; ++t) acc[t] = f32x4{0.f, 0.f, 0.f, 0.f};
        #pragma unroll
        for (int t = 0; t < 4; ++t) accI[t] = f32x4{0.f, 0.f, 0.f, 0.f};
        gemmW<4>(wbuf + 64*72, ml, q, B, acc);
        gemmW<1>(wbuf + 128*72, ml, q, B, accI);

        // s_inf -> e (lane = p)
        if (q == 0) {
            #pragma unroll
            for (int pt = 0; pt < 4; ++pt) sbuf[wv][pt*16 + ml] = accI[pt][0] + binf;
        }
        {
            float sv = sbuf[wv][lane];
            float ea = (jg == i) ? 0.0f : 1.0f / (1.0f + __expf(-sv));
            sbuf[wv][lane] = ea;
        }

        // ---- m_i partial: lane=l sums e_p * m[p][l] (m still in yb) ----
        #pragma unroll 8
        for (int j2 = 0; j2 < 64; ++j2) {
            float ev = sbuf[wv][j2];
            macc += ev * bf2f(yb[j2 * 72 + lane]);
        }

        ep_silu4(yb, ml, q, acc, b_x0);     // y1 -> yb (m dead)

        // ---- phi_x L1 ----
        load_bfrags(yb, ml, q, B);
        #pragma unroll
        for (int t = 0; t < 16; ++t) acc[t] = f32x4{0.f, 0.f, 0.f, 0.f};
        gemmW<4>(wbuf + 144*72, ml, q, B, acc);
        ep_silu4(yb, ml, q, acc, b_x1);     // y2 -> yb

        // ---- phi_x L2 (4 outputs = D rows 0..3 of one tile) ----
        load_bfrags(yb, ml, q, B);
        f32x4 acc2[4];
        #pragma unroll
        for (int t = 0; t < 4; ++t) acc2[t] = f32x4{0.f, 0.f, 0.f, 0.f};
        gemmW<1>(wbuf + 208*72, ml, q, B, acc2);
        if (q == 0) {
            #pragma unroll
            for (int pt = 0; pt < 4; ++pt) {
                float4 pv = make_float4(acc2[pt][0] + b_x2.x, acc2[pt][1] + b_x2.y,
                                        acc2[pt][2] + b_x2.z, acc2[pt][3] + b_x2.w);
                *(float4*)(pbuf[wv] + (pt*16 + ml) * 4) = pv;
            }
        }

        // ---- shift contributions (lane = p), no shuffles here ----
        {
            float4 pv = *(const float4*)(pbuf[wv] + lane * 4);
            float pvh[4] = {pv.x, pv.y, pv.z, pv.w};
            float mask = (jg == i) ? 0.0f : 1.0f;
            #pragma unroll
            for (int hh = 0; hh < 4; ++hh) {
                float nsq = (sqn[hh] == 0.0f) ? 1.0f : sqn[hh];
                float inv = mask * pvh[hh] / (sqrtf(nsq) + 1.0f);
                #pragma unroll
                for (int d = 0; d < 3; ++d)
                    sacc[hh*3 + d] += dx[hh*3 + d] * inv;
            }
        }
    }

    // one butterfly at the end (was 3x per chunk)
    #pragma unroll
    for (int t = 0; t < 12; ++t) {
        float v = sacc[t];
        v += __shfl_xor(v, 1, 64);
        v += __shfl_xor(v, 2, 64);
        v += __shfl_xor(v, 4, 64);
        v += __shfl_xor(v, 8, 64);
        v += __shfl_xor(v, 16, 64);
        v += __shfl_xor(v, 32, 64);
        sacc[t] = v;
    }

    redm[wv][lane] = macc;
    if (lane == 0) {
        #pragma unroll
        for (int t = 0; t < 12; ++t) reds[wv][t] = sacc[t];
    }
    __syncthreads();

    if (wv == 0) {
        float mi = (redm[0][lane] + redm[1][lane] + redm[2][lane] + redm[3][lane])
                   * (1.0f / sqrtf(767.0f));
        inbuf[lane] = mi;

        if (lane < 12) {
            float sh = reds[0][lane] + reds[1][lane] + reds[2][lane] + reds[3][lane];
            out[i*12 + lane] = x[i*12 + lane] + sh * (1.0f / 767.0f);
        }

        float a = hb0[lane];
        #pragma unroll 8
        for (int k = 0; k < 128; ++k) a += inbuf[k] * hw0[k*64 + lane];
        zbuf[lane] = silu_f(a);

        a = hb1[lane];
        #pragma unroll 8
        for (int k = 0; k < 64; ++k) a += zbuf[k] * hw1[k*64 + lane];
        zbuf[lane] = silu_f(a);

        a = hb2[lane];
        #pragma unroll 8
        for (int k = 0; k < 64; ++k) a += zbuf[k] * hw2[k*64 + lane];
        out[9216 + i*64 + lane] = h[i*64 + lane] + a;
    }
}

extern "C" void kernel_launch(void* const* d_in, const int* in_sizes, int n_in,
                              void* d_out, int out_size, void* d_ws, size_t ws_size,
                              hipStream_t stream) {
    const float* x    = (const float*)d_in[0];
    const float* h    = (const float*)d_in[1];
    const float* ew0  = (const float*)d_in[2];
    const float* eb0  = (const float*)d_in[3];
    const float* ew1  = (const float*)d_in[4];
    const float* eb1  = (const float*)d_in[5];
    const float* infw = (const float*)d_in[6];
    const float* infb = (const float*)d_in[7];
    const float* xw0  = (const float*)d_in[8];
    const float* xb0  = (const float*)d_in[9];
    const float* xw1  = (const float*)d_in[10];
    const float* xb1  = (const float*)d_in[11];
    const float* xw2  = (const float*)d_in[12];
    const float* xb2  = (const float*)d_in[13];
    const float* hw0  = (const float*)d_in[14];
    const float* hb0  = (const float*)d_in[15];
    const float* hw1  = (const float*)d_in[16];
    const float* hb1  = (const float*)d_in[17];
    const float* hw2  = (const float*)d_in[18];
    const float* hb2  = (const float*)d_in[19];

    float* ws  = (float*)d_ws;
    float* out = (float*)d_out;

    prep_kernel<<<801, 64, 0, stream>>>(x, h, ew0, eb0, ew1, eb1, infw, infb,
                                        xw0, xb0, xw1, xb1, xw2, xb2, ws);
    egcl_kernel<<<768, 256, 0, stream>>>(x, h, hw0, hb0, hw1, hb1, hw2, hb2, ws, out);
}